// Round 1
// baseline (11.006 us; speedup 1.0000x reference)
//
#include <hip/hip_runtime.h>
#include <hip/hip_bf16.h>

// out[b] = v[ sum_d obs[b][d] << d ]  -- exact-match table lookup.
// The reference's two-GEMM indicator construction is a one-hot match of
// obs[b,:] against the full 2^16 enumeration stored in mask, where
// mask[n,d] = 2*((n>>d)&1)-1. Hence the matching row index is simply the
// bit-packed observation.

__global__ __launch_bounds__(256) void critic_tab_gather(
    const int* __restrict__ obs,   // [B,16] int32 in {0,1}
    const float* __restrict__ v,   // [65536] float32
    float* __restrict__ out,       // [B] float32
    int B)
{
    int b = blockIdx.x * blockDim.x + threadIdx.x;
    if (b >= B) return;

    // 16 int32 per row = 64 bytes = four int4 vector loads, coalesced enough
    // at this tiny size (thread b reads a contiguous 64B chunk).
    const int4* o = reinterpret_cast<const int4*>(obs + (size_t)b * 16);
    int4 a0 = o[0];
    int4 a1 = o[1];
    int4 a2 = o[2];
    int4 a3 = o[3];

    unsigned idx = 0;
    idx |= (unsigned)(a0.x & 1) << 0;
    idx |= (unsigned)(a0.y & 1) << 1;
    idx |= (unsigned)(a0.z & 1) << 2;
    idx |= (unsigned)(a0.w & 1) << 3;
    idx |= (unsigned)(a1.x & 1) << 4;
    idx |= (unsigned)(a1.y & 1) << 5;
    idx |= (unsigned)(a1.z & 1) << 6;
    idx |= (unsigned)(a1.w & 1) << 7;
    idx |= (unsigned)(a2.x & 1) << 8;
    idx |= (unsigned)(a2.y & 1) << 9;
    idx |= (unsigned)(a2.z & 1) << 10;
    idx |= (unsigned)(a2.w & 1) << 11;
    idx |= (unsigned)(a3.x & 1) << 12;
    idx |= (unsigned)(a3.y & 1) << 13;
    idx |= (unsigned)(a3.z & 1) << 14;
    idx |= (unsigned)(a3.w & 1) << 15;

    out[b] = v[idx];
}

extern "C" void kernel_launch(void* const* d_in, const int* in_sizes, int n_in,
                              void* d_out, int out_size, void* d_ws, size_t ws_size,
                              hipStream_t stream) {
    const int* obs  = (const int*)d_in[0];     // [B,16]
    // d_in[1] = mask [N,16] -- unused; its enumeration is the index formula.
    const float* v  = (const float*)d_in[2];   // [N]
    float* out      = (float*)d_out;           // [B]

    int B = in_sizes[0] / 16;
    int block = 256;
    int grid = (B + block - 1) / block;
    critic_tab_gather<<<grid, block, 0, stream>>>(obs, v, out, B);
}